// Round 5
// baseline (922.717 us; speedup 1.0000x reference)
//
#include <hip/hip_runtime.h>
#include <hip/hip_bf16.h>
#include <math.h>

typedef unsigned short u16;
typedef __bf16 bf16x8 __attribute__((ext_vector_type(8)));
typedef float f32x4 __attribute__((ext_vector_type(4)));

#define B_ 4
#define N_ 1024
#define DIM_ 256
#define HEADS_ 4
#define DH_ 64
#define MLP_ 1024
#define DEPTH_ 4

__device__ __forceinline__ float r2f(u16 r){ return __uint_as_float(((unsigned)r)<<16); }
__device__ __forceinline__ u16 f2r(float f){ __hip_bfloat16 h = __float2bfloat16(f); return *(u16*)&h; }

__device__ __forceinline__ float gelu_exact(float v){
  return 0.5f*v*(1.0f + erff(v*0.70710678118654752440f));
}

#define MFMA16(a,b,c) __builtin_amdgcn_mfma_f32_16x16x32_bf16(a,b,c,0,0,0)

// ---------------- fused prep: blocks [0,4096): bias prep ; [4096,4608): LN1(x) ----------------
__global__ void prep_fused(const float* __restrict__ bias, u16* __restrict__ G, u16* __restrict__ bsum,
                           const float* __restrict__ X, u16* __restrict__ Y,
                           const float* __restrict__ g, const float* __restrict__ bvec){
  if (blockIdx.x < 4096){
    int blk = blockIdx.x;           // b*N + i
    int i = blk & (N_-1);
    int b = blk >> 10;
    int t = threadIdx.x;
    __shared__ float red[256];
    long long base0 = ((long long)(b*HEADS_)*N_ + i)*(long long)N_;
    const long long hs = (long long)N_*N_;
    const long long cs = (long long)B_*HEADS_*N_*N_;
    int j0 = t*4;
    f32x4 a = {0.f,0.f,0.f,0.f}, s = {0.f,0.f,0.f,0.f};
    #pragma unroll
    for (int h=0;h<HEADS_;h++){
      f32x4 x0 = *(const f32x4*)(bias + base0 + h*hs + j0);
      f32x4 x1 = *(const f32x4*)(bias + cs + base0 + h*hs + j0);
      a += x0; s += x1;
      union { ushort4 u; u16 e[4]; } pk;
      #pragma unroll
      for (int k=0;k<4;k++) pk.e[k] = f2r(x0[k]+x1[k]);
      *(ushort4*)(bsum + base0 + h*hs + j0) = pk.u;
    }
    float v[4]; float lmax = -3e38f;
    #pragma unroll
    for (int k=0;k<4;k++){ v[k] = (a[k]*0.25f)*(s[k]*0.25f); lmax = fmaxf(lmax, v[k]); }
    red[t]=lmax; __syncthreads();
    for (int st=128;st>0;st>>=1){ if(t<st) red[t]=fmaxf(red[t],red[t+st]); __syncthreads(); }
    float m = red[0]; __syncthreads();
    float e[4]; float lsum = 0.f;
    #pragma unroll
    for (int k=0;k<4;k++){ e[k] = __expf(v[k]-m); lsum += e[k]; }
    red[t]=lsum; __syncthreads();
    for (int st=128;st>0;st>>=1){ if(t<st) red[t]+=red[t+st]; __syncthreads(); }
    float inv = 1.0f/red[0];
    u16* Grow = G + ((long long)b*N_ + i)*(long long)N_;
    union { ushort4 u; u16 e[4]; } pg;
    #pragma unroll
    for (int k=0;k<4;k++) pg.e[k] = f2r(e[k]*inv);
    *(ushort4*)(Grow + j0) = pg.u;
  } else {
    int row = (blockIdx.x-4096)*8 + (threadIdx.x>>5);
    int cg = threadIdx.x&31;
    const float* xp = X + (long long)row*DIM_ + cg*8;
    f32x4 v0 = *(const f32x4*)xp;
    f32x4 v1 = *(const f32x4*)(xp+4);
    float s = v0[0]+v0[1]+v0[2]+v0[3]+v1[0]+v1[1]+v1[2]+v1[3];
    s += __shfl_xor(s,1); s += __shfl_xor(s,2); s += __shfl_xor(s,4); s += __shfl_xor(s,8); s += __shfl_xor(s,16);
    float mu = s*(1.0f/256.0f);
    float s2 = 0.f;
    #pragma unroll
    for (int k=0;k<4;k++){ float d=v0[k]-mu; s2 += d*d; }
    #pragma unroll
    for (int k=0;k<4;k++){ float d=v1[k]-mu; s2 += d*d; }
    s2 += __shfl_xor(s2,1); s2 += __shfl_xor(s2,2); s2 += __shfl_xor(s2,4); s2 += __shfl_xor(s2,8); s2 += __shfl_xor(s2,16);
    float rstd = rsqrtf(s2*(1.0f/256.0f)+1e-5f);
    f32x4 g0 = *(const f32x4*)(g + cg*8);
    f32x4 g1 = *(const f32x4*)(g + cg*8 + 4);
    f32x4 b0 = *(const f32x4*)(bvec + cg*8);
    f32x4 b1 = *(const f32x4*)(bvec + cg*8 + 4);
    union { ushort4 u[2]; u16 e[8]; } pk;
    #pragma unroll
    for (int k=0;k<4;k++) pk.e[k]   = f2r((v0[k]-mu)*rstd*g0[k] + b0[k]);
    #pragma unroll
    for (int k=0;k<4;k++) pk.e[4+k] = f2r((v1[k]-mu)*rstd*g1[k] + b1[k]);
    u16* yp = Y + (long long)row*DIM_ + cg*8;
    *(ushort4*)yp = pk.u[0];
    *(ushort4*)(yp+4) = pk.u[1];
  }
}

// ---------------- one-shot transpose+cast of all weights + x ----------------
__global__ void tcast_all(const float* __restrict__ Wkv, const float* __restrict__ Wq,
                          const float* __restrict__ Wo, const float* __restrict__ W1,
                          const float* __restrict__ W2, const float* __restrict__ Wg,
                          const float* __restrict__ xin,
                          u16* WkvT, u16* WqT, u16* WoT, u16* W1T, u16* W2T, u16* WgT, u16* xT){
  int z = blockIdx.z;
  const float* I; u16* O; int ldin, R, C;
  if (z < 4)       { I = Wkv + z*131072;      O = WkvT + z*131072;      ldin=512;  R=256;  C=512;  }
  else if (z < 8)  { I = Wq  + (z-4)*65536;   O = WqT  + (z-4)*65536;   ldin=256;  R=256;  C=256;  }
  else if (z < 12) { I = Wo  + (z-8)*65536;   O = WoT  + (z-8)*65536;   ldin=256;  R=256;  C=256;  }
  else if (z < 16) { I = W1  + (z-12)*262144; O = W1T  + (z-12)*262144; ldin=1024; R=256;  C=1024; }
  else if (z < 20) { I = W2  + (z-16)*262144; O = W2T  + (z-16)*262144; ldin=256;  R=1024; C=256;  }
  else if (z == 20){ I = Wg;                  O = WgT;                  ldin=256;  R=256;  C=256;  }
  else             { I = xin + (z-21)*262144; O = xT   + (z-21)*262144; ldin=256;  R=1024; C=256;  }
  int c0 = blockIdx.x*32, r0 = blockIdx.y*32;
  if (c0 >= C || r0 >= R) return;
  __shared__ float tile[32][33];
  int tx = threadIdx.x, ty = threadIdx.y;
  #pragma unroll
  for (int i=0;i<4;i++)
    tile[ty*4+i][tx] = I[(long long)(r0+ty*4+i)*ldin + c0+tx];
  __syncthreads();
  #pragma unroll
  for (int i=0;i<4;i++)
    O[(long long)(c0+ty*4+i)*R + r0+tx] = f2r(tile[tx][ty*4+i]);
}

// ================= layer_pre: grid 512. blocks [0,256): q-chain; [256,512): kv (barrier-free) =================
__global__ __launch_bounds__(512, 4) void layer_pre(
    const u16* __restrict__ Gb, const u16* __restrict__ xT, const u16* __restrict__ xnb,
    const u16* __restrict__ WgT, const u16* __restrict__ WqT, const u16* __restrict__ WkvT,
    const float* __restrict__ lng, const float* __restrict__ lnb,
    u16* __restrict__ qb, u16* __restrict__ kvb, u16* __restrict__ vt)
{
  __shared__ float Gx_s[16][264];
  __shared__ float t2_s[16][264];
  __shared__ u16  xma_s[16][264];
  int tid = threadIdx.x;
  int w = tid>>6, lane = tid&63, lr = lane&15, qd = lane>>4;
  int bid = blockIdx.x;

  if (bid >= 256){
    // ---- kv blocks: kv = xn @ Wkv -> global (+ vt transposed). No barriers.
    int row0 = (bid-256)*16;
    int batch = row0>>10;
    const u16* Ap = xnb + (long long)(row0+lr)*DIM_;
    f32x4 acc[4] = {};
    for (int k0=0;k0<256;k0+=32){
      bf16x8 af = *(const bf16x8*)(Ap + k0 + qd*8);
      #pragma unroll
      for (int i=0;i<4;i++){
        bf16x8 bf = *(const bf16x8*)(WkvT + (long long)((w*4+i)*16+lr)*256 + k0 + qd*8);
        acc[i] = MFMA16(af,bf,acc[i]);
      }
    }
    #pragma unroll
    for (int i=0;i<4;i++){
      int col = (w*4+i)*16+lr;
      #pragma unroll
      for (int r=0;r<4;r++){
        int row = row0+qd*4+r;
        float v = acc[i][r];
        kvb[(long long)row*512 + col] = f2r(v);
        if (col >= 256)
          vt[(long long)batch*262144 + (long long)(col-256)*1024 + (row&1023)] = f2r(v);
      }
    }
    return;
  }

  int row0 = bid*16;
  int batch = row0>>10, brow0 = row0&1023;

  // ---- stage1: Gx = G[rows] @ x  (kw: K-half, cw: 64-col group)
  {
    int kw = w>>2, cw = w&3;
    const u16* Ap = Gb + (long long)batch*1048576 + (long long)(brow0+lr)*1024 + kw*512;
    const u16* Bp = xT + (long long)batch*262144 + (long long)kw*512;
    f32x4 acc[4] = {};
    for (int k0=0;k0<512;k0+=32){
      bf16x8 af = *(const bf16x8*)(Ap + k0 + qd*8);
      #pragma unroll
      for (int nt=0;nt<4;nt++){
        bf16x8 bf = *(const bf16x8*)(Bp + (long long)(cw*64+nt*16+lr)*1024 + k0 + qd*8);
        acc[nt] = MFMA16(af,bf,acc[nt]);
      }
    }
    if (kw==0){
      #pragma unroll
      for (int nt=0;nt<4;nt++)
        #pragma unroll
        for (int r=0;r<4;r++) Gx_s[qd*4+r][cw*64+nt*16+lr] = acc[nt][r];
    }
    __syncthreads();
    if (kw==1){
      #pragma unroll
      for (int nt=0;nt<4;nt++)
        #pragma unroll
        for (int r=0;r<4;r++) Gx_s[qd*4+r][cw*64+nt*16+lr] += acc[nt][r];
    }
    __syncthreads();
  }
  // ---- convert Gx to bf16 into xma_s
  {
    int r = tid>>5, cg2 = tid&31;
    #pragma unroll
    for (int i=0;i<8;i++) xma_s[r][cg2*8+i] = f2r(Gx_s[r][cg2*8+i]);
  }
  __syncthreads();
  // ---- stage2: t2 = Gx @ Wg  (each wave 2 col-tiles)
  {
    f32x4 acc[2] = {};
    for (int k0=0;k0<256;k0+=32){
      bf16x8 af = *(const bf16x8*)&xma_s[lr][k0+qd*8];
      #pragma unroll
      for (int i=0;i<2;i++){
        bf16x8 bf = *(const bf16x8*)(WgT + (long long)((w*2+i)*16+lr)*256 + k0 + qd*8);
        acc[i] = MFMA16(af,bf,acc[i]);
      }
    }
    #pragma unroll
    for (int i=0;i<2;i++)
      #pragma unroll
      for (int r=0;r<4;r++) t2_s[qd*4+r][(w*2+i)*16+lr] = acc[i][r];
  }
  __syncthreads();
  // ---- LN(t2)+relu -> xma_s
  {
    int r = tid>>5, cg2 = tid&31;
    float v[8]; float s=0.f;
    #pragma unroll
    for (int i=0;i<8;i++){ v[i] = t2_s[r][cg2*8+i]; s += v[i]; }
    s += __shfl_xor(s,1); s += __shfl_xor(s,2); s += __shfl_xor(s,4); s += __shfl_xor(s,8); s += __shfl_xor(s,16);
    float mu = s*(1.0f/256.0f);
    float s2=0.f;
    #pragma unroll
    for (int i=0;i<8;i++){ float d=v[i]-mu; s2 += d*d; }
    s2 += __shfl_xor(s2,1); s2 += __shfl_xor(s2,2); s2 += __shfl_xor(s2,4); s2 += __shfl_xor(s2,8); s2 += __shfl_xor(s2,16);
    float rstd = rsqrtf(s2*(1.0f/256.0f)+1e-5f);
    #pragma unroll
    for (int i=0;i<8;i++){
      int c = cg2*8+i;
      float y = (v[i]-mu)*rstd*lng[c] + lnb[c];
      xma_s[r][c] = f2r(fmaxf(y,0.f));
    }
  }
  __syncthreads();
  // ---- stage3: q = xma @ Wq -> global
  {
    f32x4 acc[2] = {};
    for (int k0=0;k0<256;k0+=32){
      bf16x8 af = *(const bf16x8*)&xma_s[lr][k0+qd*8];
      #pragma unroll
      for (int i=0;i<2;i++){
        bf16x8 bf = *(const bf16x8*)(WqT + (long long)((w*2+i)*16+lr)*256 + k0 + qd*8);
        acc[i] = MFMA16(af,bf,acc[i]);
      }
    }
    #pragma unroll
    for (int i=0;i<2;i++)
      #pragma unroll
      for (int r=0;r<4;r++)
        qb[(long long)(row0+qd*4+r)*DIM_ + (w*2+i)*16+lr] = f2r(acc[i][r]);
  }
}

// ================= attn_post: fused attention + Wo/LN2/MLP/LN1'. grid 512 x 512 thr, 8 rows/block =================
// MFMA tiles stay 16 rows; rows 8-15 duplicate rows 0-7 (issue waste, but enables 2 blocks/CU).
// All global stores guarded to rows < 8; duplicated-row global reads clamped with &7 (no OOB).
// LDS overlay (bytes): A: sb@0(18432) Pl@18432(18432) Ol@36864(34816) Ml@71680 Ll@72192 -> 72704
//                      ao_s@0(8448) | B: v_s@8448(16896) xn2@25344(8448) h1@33792(33536) xnew@33792(overlay)
#define APSMEM 72704
__global__ __launch_bounds__(512, 4) void attn_post(
    const u16* __restrict__ qb, const u16* __restrict__ kvb,
    const u16* __restrict__ vt, const u16* __restrict__ bsum,
    const float* __restrict__ resx,
    const u16* __restrict__ WoT, const float* __restrict__ bo,
    const float* __restrict__ ln2g, const float* __restrict__ ln2b,
    const u16* __restrict__ W1T, const float* __restrict__ b1,
    const u16* __restrict__ W2T, const float* __restrict__ b2,
    float* __restrict__ xf_out,
    const float* __restrict__ ln1g_next, const float* __restrict__ ln1b_next,
    u16* __restrict__ xn_out, u16* __restrict__ xT_out)
{
  __shared__ __align__(16) char smem[APSMEM];
  u16 (*sb)[16][72]   = (u16 (*)[16][72])smem;
  u16 (*Pl)[16][72]   = (u16 (*)[16][72])(smem+18432);
  float (*Ol)[16][68] = (float(*)[16][68])(smem+36864);
  float (*Ml)[16]     = (float(*)[16])(smem+71680);
  float (*Ll)[16]     = (float(*)[16])(smem+72192);
  u16  (*ao_s)[264]   = (u16 (*)[264])smem;
  float (*v_s)[264]   = (float(*)[264])(smem+8448);
  u16  (*xn2_s)[264]  = (u16 (*)[264])(smem+25344);
  u16  (*h1_s)[1048]  = (u16 (*)[1048])(smem+33792);
  float (*xnew_s)[264]= (float(*)[264])(smem+33792);

  int tid = threadIdx.x;
  int w = tid>>6, lane = tid&63, lr = lane&15, qd = lane>>4;
  int row0 = blockIdx.x*8;                  // 8 rows per block
  int batch = row0>>10, brow0 = row0&1023;

  // ================= phase A: attention =================
  {
    int h = w>>1, g = w&1;
    int z = batch*HEADS_ + h;
    const u16* qp = qb + ((long long)row0 + (lr&7))*DIM_ + h*DH_;   // rows 8-15 dup 0-7
    bf16x8 aq0 = *(const bf16x8*)(qp + qd*8);
    bf16x8 aq1 = *(const bf16x8*)(qp + 32 + qd*8);

    f32x4 oacc[4] = {};
    float m_r[4] = {-3e38f,-3e38f,-3e38f,-3e38f};
    float l_r[4] = {0.f,0.f,0.f,0.f};

    const u16* kbase = kvb + ((long long)(batch*N_))*512 + h*DH_;
    const u16* vbase = vt + (long long)batch*(DIM_*N_) + (long long)(h*DH_)*N_;
    const u16* bias_base = bsum + ((long long)z*N_ + brow0)*(long long)N_;
    int srr = lane>>2, scc = (lane&3)*16;

    for (int jtl=0; jtl<8; jtl++){
      int j0 = (g*8 + jtl)*64;
      {
        const u16* gs = bias_base + (long long)(srr&7)*N_ + j0 + scc;  // clamp to 8 valid rows
        uint4 t0 = *(const uint4*)gs;
        uint4 t1 = *(const uint4*)(gs+8);
        *(uint4*)&sb[w][srr][scc]   = t0;
        *(uint4*)&sb[w][srr][scc+8] = t1;
      }
      f32x4 sacc[4] = {};
      #pragma unroll
      for (int nt=0; nt<4; nt++){
        const u16* kp = kbase + (long long)(j0 + nt*16 + lr)*512;
        bf16x8 bk0 = *(const bf16x8*)(kp + qd*8);
        bf16x8 bk1 = *(const bf16x8*)(kp + 32 + qd*8);
        sacc[nt] = MFMA16(aq0, bk0, sacc[nt]);
        sacc[nt] = MFMA16(aq1, bk1, sacc[nt]);
      }
      #pragma unroll
      for (int r=0;r<4;r++){
        float pv[4];
        float vmax = -3e38f;
        #pragma unroll
        for (int nt=0;nt<4;nt++){
          float v = sacc[nt][r]*0.0625f + r2f(sb[w][qd*4+r][nt*16+lr]);
          pv[nt] = v;
          vmax = fmaxf(vmax, v);
        }
        vmax = fmaxf(vmax, __shfl_xor(vmax,1));
        vmax = fmaxf(vmax, __shfl_xor(vmax,2));
        vmax = fmaxf(vmax, __shfl_xor(vmax,4));
        vmax = fmaxf(vmax, __shfl_xor(vmax,8));
        float newm = fmaxf(m_r[r], vmax);
        float alpha = __expf(m_r[r]-newm);
        m_r[r] = newm;
        float psum = 0.f;
        #pragma unroll
        for (int nt=0;nt<4;nt++){
          float p = __expf(pv[nt]-newm);
          psum += p;
          Pl[w][qd*4+r][nt*16+lr] = f2r(p);
        }
        psum += __shfl_xor(psum,1);
        psum += __shfl_xor(psum,2);
        psum += __shfl_xor(psum,4);
        psum += __shfl_xor(psum,8);
        l_r[r] = l_r[r]*alpha + psum;
        #pragma unroll
        for (int ot=0;ot<4;ot++) oacc[ot][r] *= alpha;
      }
      #pragma unroll
      for (int ks=0;ks<2;ks++){
        bf16x8 ap = *(const bf16x8*)&Pl[w][lr][ks*32 + qd*8];
        #pragma unroll
        for (int ot=0;ot<4;ot++){
          const u16* vp = vbase + (long long)(ot*16+lr)*N_ + j0 + ks*32 + qd*8;
          bf16x8 bv = *(const bf16x8*)vp;
          oacc[ot] = MFMA16(ap, bv, oacc[ot]);
        }
      }
    }
    #pragma unroll
    for (int r=0;r<4;r++){
      int row = qd*4+r;
      #pragma unroll
      for (int ot=0;ot<4;ot++) Ol[w][row][ot*16+lr] = oacc[ot][r];
      if (lr==0){ Ml[w][row] = m_r[r]; Ll[w][row] = l_r[r]; }
    }
  }
  __syncthreads();
  // ---- merge halves (even wave merges with odd partner) -> ao_s (bf16; dup rows kept)
  if (!(w&1)){
    int h = w>>1;
    #pragma unroll
    for (int r=0;r<4;r++){
      int row = qd*4+r;
      float m0 = Ml[w][row], m1 = Ml[w+1][row];
      float mm = fmaxf(m0,m1);
      float e0 = __expf(m0-mm), e1 = __expf(m1-mm);
      float inv = 1.0f/(Ll[w][row]*e0 + Ll[w+1][row]*e1);
      #pragma unroll
      for (int ot=0;ot<4;ot++){
        float o = Ol[w][row][ot*16+lr]*e0 + Ol[w+1][row][ot*16+lr]*e1;
        ao_s[row][h*DH_ + ot*16+lr] = f2r(o*inv);
      }
    }
  }
  __syncthreads();

  // ================= phase B: Wo+res -> LN2 -> W1+gelu -> W2+res -> LN1' =================
  // ---- stage1: x' = ao@Wo + bo + resx -> v_s
  {
    f32x4 acc[2] = {};
    for (int k0=0;k0<256;k0+=32){
      bf16x8 af = *(const bf16x8*)&ao_s[lr][k0+qd*8];
      #pragma unroll
      for (int i=0;i<2;i++){
        bf16x8 bf = *(const bf16x8*)(WoT + (long long)((w*2+i)*16+lr)*256 + k0 + qd*8);
        acc[i] = MFMA16(af,bf,acc[i]);
      }
    }
    #pragma unroll
    for (int i=0;i<2;i++){
      int col = (w*2+i)*16+lr;
      #pragma unroll
      for (int r=0;r<4;r++)
        v_s[qd*4+r][col] = acc[i][r] + bo[col]
                         + resx[(long long)(row0+((qd*4+r)&7))*DIM_ + col];  // clamp
    }
  }
  __syncthreads();
  // ---- LN2 -> xn2_s
  {
    int r = tid>>5, cg2 = tid&31;
    float v[8]; float s=0.f;
    #pragma unroll
    for (int i=0;i<8;i++){ v[i] = v_s[r][cg2*8+i]; s += v[i]; }
    s += __shfl_xor(s,1); s += __shfl_xor(s,2); s += __shfl_xor(s,4); s += __shfl_xor(s,8); s += __shfl_xor(s,16);
    float mu = s*(1.0f/256.0f);
    float s2=0.f;
    #pragma unroll
    for (int i=0;i<8;i++){ float d=v[i]-mu; s2 += d*d; }
    s2 += __shfl_xor(s2,1); s2 += __shfl_xor(s2,2); s2 += __shfl_xor(s2,4); s2 += __shfl_xor(s2,8); s2 += __shfl_xor(s2,16);
    float rstd = rsqrtf(s2*(1.0f/256.0f)+1e-5f);
    #pragma unroll
    for (int i=0;i<8;i++){
      int c = cg2*8+i;
      xn2_s[r][c] = f2r((v[i]-mu)*rstd*ln2g[c] + ln2b[c]);
    }
  }
  __syncthreads();
  // ---- stage2: h1 = gelu(xn2 @ W1 + b1) -> h1_s
  {
    f32x4 acc[8] = {};
    for (int k0=0;k0<256;k0+=32){
      bf16x8 af = *(const bf16x8*)&xn2_s[lr][k0+qd*8];
      #pragma unroll
      for (int i=0;i<8;i++){
        bf16x8 bf = *(const bf16x8*)(W1T + (long long)((w*8+i)*16+lr)*256 + k0 + qd*8);
        acc[i] = MFMA16(af,bf,acc[i]);
      }
    }
    #pragma unroll
    for (int i=0;i<8;i++){
      int col = (w*8+i)*16+lr;
      #pragma unroll
      for (int r=0;r<4;r++)
        h1_s[qd*4+r][col] = f2r(gelu_exact(acc[i][r] + b1[col]));
    }
  }
  __syncthreads();
  // ---- stage3: x_new = h1 @ W2 + b2 + x' -> xf_out (rows<8) (+ xnew_s overlaying h1 after barrier)
  {
    f32x4 acc[2] = {};
    for (int k0=0;k0<1024;k0+=32){
      bf16x8 af = *(const bf16x8*)&h1_s[lr][k0+qd*8];
      #pragma unroll
      for (int i=0;i<2;i++){
        bf16x8 bf = *(const bf16x8*)(W2T + (long long)((w*2+i)*16+lr)*1024 + k0 + qd*8);
        acc[i] = MFMA16(af,bf,acc[i]);
      }
    }
    __syncthreads();   // all h1 reads complete before xnew_s overlays h1_s
    #pragma unroll
    for (int i=0;i<2;i++){
      int col = (w*2+i)*16+lr;
      #pragma unroll
      for (int r=0;r<4;r++){
        int row = qd*4+r;
        float v = acc[i][r] + b2[col] + v_s[row][col];
        if (row < 8)
          xf_out[(long long)(row0+row)*DIM_ + col] = v;
        xnew_s[row][col] = v;
      }
    }
  }
  if (ln1g_next){
    __syncthreads();
    int r = tid>>5, cg2 = tid&31;
    float v[8]; float s=0.f;
    #pragma unroll
    for (int i=0;i<8;i++){ v[i] = xnew_s[r][cg2*8+i]; s += v[i]; }
    s += __shfl_xor(s,1); s += __shfl_xor(s,2); s += __shfl_xor(s,4); s += __shfl_xor(s,8); s += __shfl_xor(s,16);
    float mu = s*(1.0f/256.0f);
    float s2=0.f;
    #pragma unroll
    for (int i=0;i<8;i++){ float d=v[i]-mu; s2 += d*d; }
    s2 += __shfl_xor(s2,1); s2 += __shfl_xor(s2,2); s2 += __shfl_xor(s2,4); s2 += __shfl_xor(s2,8); s2 += __shfl_xor(s2,16);
    float rstd = rsqrtf(s2*(1.0f/256.0f)+1e-5f);
    if (r < 8){
      int grow = row0 + r;
      #pragma unroll
      for (int i=0;i<8;i++){
        int c = cg2*8+i;
        xn_out[(long long)grow*DIM_ + c] = f2r((v[i]-mu)*rstd*ln1g_next[c] + ln1b_next[c]);
        xT_out[(long long)batch*262144 + (long long)c*1024 + (grow&1023)] = f2r(v[i]);
      }
    }
  }
}

// ---------------- host launch ----------------
extern "C" void kernel_launch(void* const* d_in, const int* in_sizes, int n_in,
                              void* d_out, int out_size, void* d_ws, size_t ws_size,
                              hipStream_t stream){
  const float* x_in   = (const float*)d_in[0];
  const float* abias  = (const float*)d_in[1];
  const float* ln1_g  = (const float*)d_in[2];
  const float* ln1_b  = (const float*)d_in[3];
  const float* Wkv    = (const float*)d_in[4];
  const float* Wq     = (const float*)d_in[5];
  const float* Wo     = (const float*)d_in[6];
  const float* bo     = (const float*)d_in[7];
  const float* ln2_g  = (const float*)d_in[8];
  const float* ln2_b  = (const float*)d_in[9];
  const float* W1     = (const float*)d_in[10];
  const float* b1     = (const float*)d_in[11];
  const float* W2     = (const float*)d_in[12];
  const float* b2     = (const float*)d_in[13];
  const float* Wg     = (const float*)d_in[14];
  const float* lng_g  = (const float*)d_in[15];
  const float* lng_b  = (const float*)d_in[16];

  char* ws = (char*)d_ws;
  float* xf   = (float*)(ws);                               // 4 MB fp32 residual
  u16*  Gb    = (u16*)(ws + (4ll<<20));                     // 8 MB
  u16*  bsum  = (u16*)(ws + (12ll<<20));                    // 32 MB
  u16*  kvb   = (u16*)(ws + (44ll<<20));                    // 4 MB
  u16*  vt    = (u16*)(ws + (48ll<<20));                    // 2 MB
  u16*  xT    = (u16*)(ws + (50ll<<20));                    // 2 MB
  u16*  xnb   = (u16*)(ws + (52ll<<20));                    // 2 MB
  u16*  qb    = (u16*)(ws + (54ll<<20));                    // 2 MB
  u16*  WkvT  = (u16*)(ws + (58ll<<20));                    // 1 MB
  u16*  WqT   = (u16*)(ws + (59ll<<20));                    // 0.5 MB
  u16*  WoT   = (u16*)(ws + (59ll<<20) + (512ll<<10));      // 0.5 MB
  u16*  W1T   = (u16*)(ws + (60ll<<20));                    // 2 MB
  u16*  W2T   = (u16*)(ws + (62ll<<20));                    // 2 MB
  u16*  WgT   = (u16*)(ws + (64ll<<20));                    // 0.125 MB

  prep_fused<<<dim3(4608), dim3(256), 0, stream>>>(abias, Gb, bsum, x_in, xnb, ln1_g, ln1_b);
  tcast_all<<<dim3(32,32,25), dim3(32,8), 0, stream>>>(Wkv,Wq,Wo,W1,W2,Wg,x_in,
                                                       WkvT,WqT,WoT,W1T,W2T,WgT,xT);

  for (int l=0; l<DEPTH_; l++){
    const float* resx = (l==0) ? x_in : xf;
    layer_pre<<<dim3(512), dim3(512), 0, stream>>>(Gb, xT, xnb,
        WgT, WqT + (long long)l*65536, WkvT + (long long)l*131072,
        lng_g, lng_b, qb, kvb, vt);
    if (l < DEPTH_-1){
      attn_post<<<dim3(512), dim3(512), 0, stream>>>(qb, kvb, vt, bsum, resx,
          WoT + (long long)l*65536, bo + l*DIM_, ln2_g + l*DIM_, ln2_b + l*DIM_,
          W1T + (long long)l*262144, b1 + l*MLP_, W2T + (long long)l*262144, b2 + l*DIM_,
          xf, ln1_g + (l+1)*DIM_, ln1_b + (l+1)*DIM_, xnb, xT);
    } else {
      attn_post<<<dim3(512), dim3(512), 0, stream>>>(qb, kvb, vt, bsum, resx,
          WoT + (long long)l*65536, bo + l*DIM_, ln2_g + l*DIM_, ln2_b + l*DIM_,
          W1T + (long long)l*262144, b1 + l*MLP_, W2T + (long long)l*262144, b2 + l*DIM_,
          (float*)d_out, nullptr, nullptr, nullptr, nullptr);
    }
  }
}

// Round 6
// 702.453 us; speedup vs baseline: 1.3136x; 1.3136x over previous
//
#include <hip/hip_runtime.h>
#include <hip/hip_bf16.h>
#include <math.h>

typedef unsigned short u16;
typedef __bf16 bf16x8 __attribute__((ext_vector_type(8)));
typedef float f32x4 __attribute__((ext_vector_type(4)));

#define B_ 4
#define N_ 1024
#define DIM_ 256
#define HEADS_ 4
#define DH_ 64
#define MLP_ 1024
#define DEPTH_ 4

__device__ __forceinline__ float r2f(u16 r){ return __uint_as_float(((unsigned)r)<<16); }
__device__ __forceinline__ u16 f2r(float f){ __hip_bfloat16 h = __float2bfloat16(f); return *(u16*)&h; }

__device__ __forceinline__ float gelu_exact(float v){
  return 0.5f*v*(1.0f + erff(v*0.70710678118654752440f));
}

#define MFMA16(a,b,c) __builtin_amdgcn_mfma_f32_16x16x32_bf16(a,b,c,0,0,0)

// ---------------- fused prep: blocks [0,4096): bias prep ; [4096,4608): LN1(x) ----------------
__global__ void prep_fused(const float* __restrict__ bias, u16* __restrict__ G, u16* __restrict__ bsum,
                           const float* __restrict__ X, u16* __restrict__ Y,
                           const float* __restrict__ g, const float* __restrict__ bvec){
  if (blockIdx.x < 4096){
    int blk = blockIdx.x;           // b*N + i
    int i = blk & (N_-1);
    int b = blk >> 10;
    int t = threadIdx.x;
    __shared__ float red[256];
    long long base0 = ((long long)(b*HEADS_)*N_ + i)*(long long)N_;
    const long long hs = (long long)N_*N_;
    const long long cs = (long long)B_*HEADS_*N_*N_;
    int j0 = t*4;
    f32x4 a = {0.f,0.f,0.f,0.f}, s = {0.f,0.f,0.f,0.f};
    #pragma unroll
    for (int h=0;h<HEADS_;h++){
      f32x4 x0 = *(const f32x4*)(bias + base0 + h*hs + j0);
      f32x4 x1 = *(const f32x4*)(bias + cs + base0 + h*hs + j0);
      a += x0; s += x1;
      union { ushort4 u; u16 e[4]; } pk;
      #pragma unroll
      for (int k=0;k<4;k++) pk.e[k] = f2r(x0[k]+x1[k]);
      *(ushort4*)(bsum + base0 + h*hs + j0) = pk.u;
    }
    float v[4]; float lmax = -3e38f;
    #pragma unroll
    for (int k=0;k<4;k++){ v[k] = (a[k]*0.25f)*(s[k]*0.25f); lmax = fmaxf(lmax, v[k]); }
    red[t]=lmax; __syncthreads();
    for (int st=128;st>0;st>>=1){ if(t<st) red[t]=fmaxf(red[t],red[t+st]); __syncthreads(); }
    float m = red[0]; __syncthreads();
    float e[4]; float lsum = 0.f;
    #pragma unroll
    for (int k=0;k<4;k++){ e[k] = __expf(v[k]-m); lsum += e[k]; }
    red[t]=lsum; __syncthreads();
    for (int st=128;st>0;st>>=1){ if(t<st) red[t]+=red[t+st]; __syncthreads(); }
    float inv = 1.0f/red[0];
    u16* Grow = G + ((long long)b*N_ + i)*(long long)N_;
    union { ushort4 u; u16 e[4]; } pg;
    #pragma unroll
    for (int k=0;k<4;k++) pg.e[k] = f2r(e[k]*inv);
    *(ushort4*)(Grow + j0) = pg.u;
  } else {
    int row = (blockIdx.x-4096)*8 + (threadIdx.x>>5);
    int cg = threadIdx.x&31;
    const float* xp = X + (long long)row*DIM_ + cg*8;
    f32x4 v0 = *(const f32x4*)xp;
    f32x4 v1 = *(const f32x4*)(xp+4);
    float s = v0[0]+v0[1]+v0[2]+v0[3]+v1[0]+v1[1]+v1[2]+v1[3];
    s += __shfl_xor(s,1); s += __shfl_xor(s,2); s += __shfl_xor(s,4); s += __shfl_xor(s,8); s += __shfl_xor(s,16);
    float mu = s*(1.0f/256.0f);
    float s2 = 0.f;
    #pragma unroll
    for (int k=0;k<4;k++){ float d=v0[k]-mu; s2 += d*d; }
    #pragma unroll
    for (int k=0;k<4;k++){ float d=v1[k]-mu; s2 += d*d; }
    s2 += __shfl_xor(s2,1); s2 += __shfl_xor(s2,2); s2 += __shfl_xor(s2,4); s2 += __shfl_xor(s2,8); s2 += __shfl_xor(s2,16);
    float rstd = rsqrtf(s2*(1.0f/256.0f)+1e-5f);
    f32x4 g0 = *(const f32x4*)(g + cg*8);
    f32x4 g1 = *(const f32x4*)(g + cg*8 + 4);
    f32x4 b0 = *(const f32x4*)(bvec + cg*8);
    f32x4 b1 = *(const f32x4*)(bvec + cg*8 + 4);
    union { ushort4 u[2]; u16 e[8]; } pk;
    #pragma unroll
    for (int k=0;k<4;k++) pk.e[k]   = f2r((v0[k]-mu)*rstd*g0[k] + b0[k]);
    #pragma unroll
    for (int k=0;k<4;k++) pk.e[4+k] = f2r((v1[k]-mu)*rstd*g1[k] + b1[k]);
    u16* yp = Y + (long long)row*DIM_ + cg*8;
    *(ushort4*)yp = pk.u[0];
    *(ushort4*)(yp+4) = pk.u[1];
  }
}

// ---------------- one-shot transpose+cast of all weights + x ----------------
__global__ void tcast_all(const float* __restrict__ Wkv, const float* __restrict__ Wq,
                          const float* __restrict__ Wo, const float* __restrict__ W1,
                          const float* __restrict__ W2, const float* __restrict__ Wg,
                          const float* __restrict__ xin,
                          u16* WkvT, u16* WqT, u16* WoT, u16* W1T, u16* W2T, u16* WgT, u16* xT){
  int z = blockIdx.z;
  const float* I; u16* O; int ldin, R, C;
  if (z < 4)       { I = Wkv + z*131072;      O = WkvT + z*131072;      ldin=512;  R=256;  C=512;  }
  else if (z < 8)  { I = Wq  + (z-4)*65536;   O = WqT  + (z-4)*65536;   ldin=256;  R=256;  C=256;  }
  else if (z < 12) { I = Wo  + (z-8)*65536;   O = WoT  + (z-8)*65536;   ldin=256;  R=256;  C=256;  }
  else if (z < 16) { I = W1  + (z-12)*262144; O = W1T  + (z-12)*262144; ldin=1024; R=256;  C=1024; }
  else if (z < 20) { I = W2  + (z-16)*262144; O = W2T  + (z-16)*262144; ldin=256;  R=1024; C=256;  }
  else if (z == 20){ I = Wg;                  O = WgT;                  ldin=256;  R=256;  C=256;  }
  else             { I = xin + (z-21)*262144; O = xT   + (z-21)*262144; ldin=256;  R=1024; C=256;  }
  int c0 = blockIdx.x*32, r0 = blockIdx.y*32;
  if (c0 >= C || r0 >= R) return;
  __shared__ float tile[32][33];
  int tx = threadIdx.x, ty = threadIdx.y;
  #pragma unroll
  for (int i=0;i<4;i++)
    tile[ty*4+i][tx] = I[(long long)(r0+ty*4+i)*ldin + c0+tx];
  __syncthreads();
  #pragma unroll
  for (int i=0;i<4;i++)
    O[(long long)(c0+ty*4+i)*R + r0+tx] = f2r(tile[tx][ty*4+i]);
}

// ================= layer_pre: grid 512. blocks [0,256): q-chain; [256,512): kv (barrier-free) =================
__global__ __launch_bounds__(512, 4) void layer_pre(
    const u16* __restrict__ Gb, const u16* __restrict__ xT, const u16* __restrict__ xnb,
    const u16* __restrict__ WgT, const u16* __restrict__ WqT, const u16* __restrict__ WkvT,
    const float* __restrict__ lng, const float* __restrict__ lnb,
    u16* __restrict__ qb, u16* __restrict__ kvb, u16* __restrict__ vt)
{
  __shared__ float Gx_s[16][264];
  __shared__ float t2_s[16][264];
  __shared__ u16  xma_s[16][264];
  int tid = threadIdx.x;
  int w = tid>>6, lane = tid&63, lr = lane&15, qd = lane>>4;
  int bid = blockIdx.x;

  if (bid >= 256){
    // ---- kv blocks: kv = xn @ Wkv -> global (+ vt transposed). No barriers.
    int row0 = (bid-256)*16;
    int batch = row0>>10;
    const u16* Ap = xnb + (long long)(row0+lr)*DIM_;
    f32x4 acc[4] = {};
    for (int k0=0;k0<256;k0+=32){
      bf16x8 af = *(const bf16x8*)(Ap + k0 + qd*8);
      #pragma unroll
      for (int i=0;i<4;i++){
        bf16x8 bf = *(const bf16x8*)(WkvT + (long long)((w*4+i)*16+lr)*256 + k0 + qd*8);
        acc[i] = MFMA16(af,bf,acc[i]);
      }
    }
    #pragma unroll
    for (int i=0;i<4;i++){
      int col = (w*4+i)*16+lr;
      #pragma unroll
      for (int r=0;r<4;r++){
        int row = row0+qd*4+r;
        float v = acc[i][r];
        kvb[(long long)row*512 + col] = f2r(v);
        if (col >= 256)
          vt[(long long)batch*262144 + (long long)(col-256)*1024 + (row&1023)] = f2r(v);
      }
    }
    return;
  }

  int row0 = bid*16;
  int batch = row0>>10, brow0 = row0&1023;

  // ---- stage1: Gx = G[rows] @ x  (kw: K-half, cw: 64-col group)
  {
    int kw = w>>2, cw = w&3;
    const u16* Ap = Gb + (long long)batch*1048576 + (long long)(brow0+lr)*1024 + kw*512;
    const u16* Bp = xT + (long long)batch*262144 + (long long)kw*512;
    f32x4 acc[4] = {};
    for (int k0=0;k0<512;k0+=32){
      bf16x8 af = *(const bf16x8*)(Ap + k0 + qd*8);
      #pragma unroll
      for (int nt=0;nt<4;nt++){
        bf16x8 bf = *(const bf16x8*)(Bp + (long long)(cw*64+nt*16+lr)*1024 + k0 + qd*8);
        acc[nt] = MFMA16(af,bf,acc[nt]);
      }
    }
    if (kw==0){
      #pragma unroll
      for (int nt=0;nt<4;nt++)
        #pragma unroll
        for (int r=0;r<4;r++) Gx_s[qd*4+r][cw*64+nt*16+lr] = acc[nt][r];
    }
    __syncthreads();
    if (kw==1){
      #pragma unroll
      for (int nt=0;nt<4;nt++)
        #pragma unroll
        for (int r=0;r<4;r++) Gx_s[qd*4+r][cw*64+nt*16+lr] += acc[nt][r];
    }
    __syncthreads();
  }
  // ---- convert Gx to bf16 into xma_s
  {
    int r = tid>>5, cg2 = tid&31;
    #pragma unroll
    for (int i=0;i<8;i++) xma_s[r][cg2*8+i] = f2r(Gx_s[r][cg2*8+i]);
  }
  __syncthreads();
  // ---- stage2: t2 = Gx @ Wg  (each wave 2 col-tiles)
  {
    f32x4 acc[2] = {};
    for (int k0=0;k0<256;k0+=32){
      bf16x8 af = *(const bf16x8*)&xma_s[lr][k0+qd*8];
      #pragma unroll
      for (int i=0;i<2;i++){
        bf16x8 bf = *(const bf16x8*)(WgT + (long long)((w*2+i)*16+lr)*256 + k0 + qd*8);
        acc[i] = MFMA16(af,bf,acc[i]);
      }
    }
    #pragma unroll
    for (int i=0;i<2;i++)
      #pragma unroll
      for (int r=0;r<4;r++) t2_s[qd*4+r][(w*2+i)*16+lr] = acc[i][r];
  }
  __syncthreads();
  // ---- LN(t2)+relu -> xma_s
  {
    int r = tid>>5, cg2 = tid&31;
    float v[8]; float s=0.f;
    #pragma unroll
    for (int i=0;i<8;i++){ v[i] = t2_s[r][cg2*8+i]; s += v[i]; }
    s += __shfl_xor(s,1); s += __shfl_xor(s,2); s += __shfl_xor(s,4); s += __shfl_xor(s,8); s += __shfl_xor(s,16);
    float mu = s*(1.0f/256.0f);
    float s2=0.f;
    #pragma unroll
    for (int i=0;i<8;i++){ float d=v[i]-mu; s2 += d*d; }
    s2 += __shfl_xor(s2,1); s2 += __shfl_xor(s2,2); s2 += __shfl_xor(s2,4); s2 += __shfl_xor(s2,8); s2 += __shfl_xor(s2,16);
    float rstd = rsqrtf(s2*(1.0f/256.0f)+1e-5f);
    #pragma unroll
    for (int i=0;i<8;i++){
      int c = cg2*8+i;
      float y = (v[i]-mu)*rstd*lng[c] + lnb[c];
      xma_s[r][c] = f2r(fmaxf(y,0.f));
    }
  }
  __syncthreads();
  // ---- stage3: q = xma @ Wq -> global
  {
    f32x4 acc[2] = {};
    for (int k0=0;k0<256;k0+=32){
      bf16x8 af = *(const bf16x8*)&xma_s[lr][k0+qd*8];
      #pragma unroll
      for (int i=0;i<2;i++){
        bf16x8 bf = *(const bf16x8*)(WqT + (long long)((w*2+i)*16+lr)*256 + k0 + qd*8);
        acc[i] = MFMA16(af,bf,acc[i]);
      }
    }
    #pragma unroll
    for (int i=0;i<2;i++)
      #pragma unroll
      for (int r=0;r<4;r++)
        qb[(long long)(row0+qd*4+r)*DIM_ + (w*2+i)*16+lr] = f2r(acc[i][r]);
  }
}

// ================= attn_post: grid 256 x 1024 thr (16 waves = 4 heads x 4 KV-quarters) =================
// Phase A: each wave: head h = w>>2, quarter g = w&3, 4 KV iterations. 4-way LDS merge.
// Phase B: R3-verified 1024-thr post stages, A-operand from ao_s.
// LDS (bytes): A: sb@0(36864) Pl@36864(36864) Ml@73728(1024) Ll@74752(1024)
//              after sync: Ol@0 (69632, overlays sb+Pl) ; ao_s@75776(8448) -> total 84224
//              B: v_s@0(16896) xn2@16896(8448) h1@25344(33536) xnew@58880(16896)
#define APSMEM 84224
__global__ __launch_bounds__(1024, 4) void attn_post(
    const u16* __restrict__ qb, const u16* __restrict__ kvb,
    const u16* __restrict__ vt, const u16* __restrict__ bsum,
    const float* __restrict__ resx,
    const u16* __restrict__ WoT, const float* __restrict__ bo,
    const float* __restrict__ ln2g, const float* __restrict__ ln2b,
    const u16* __restrict__ W1T, const float* __restrict__ b1,
    const u16* __restrict__ W2T, const float* __restrict__ b2,
    float* __restrict__ xf_out,
    const float* __restrict__ ln1g_next, const float* __restrict__ ln1b_next,
    u16* __restrict__ xn_out, u16* __restrict__ xT_out)
{
  __shared__ __align__(16) char smem[APSMEM];
  u16 (*sb)[16][72]   = (u16 (*)[16][72])smem;
  u16 (*Pl)[16][72]   = (u16 (*)[16][72])(smem+36864);
  float (*Ml)[16]     = (float(*)[16])(smem+73728);
  float (*Ll)[16]     = (float(*)[16])(smem+74752);
  float (*Ol)[16][68] = (float(*)[16][68])smem;           // valid after sync #1
  u16  (*ao_s)[264]   = (u16 (*)[264])(smem+75776);
  float (*v_s)[264]   = (float(*)[264])smem;              // phase B
  u16  (*xn2_s)[264]  = (u16 (*)[264])(smem+16896);
  u16  (*h1_s)[1048]  = (u16 (*)[1048])(smem+25344);
  float (*xnew_s)[264]= (float(*)[264])(smem+58880);

  int tid = threadIdx.x;
  int w = tid>>6, lane = tid&63, lr = lane&15, qd = lane>>4;
  int row0 = blockIdx.x*16;
  int batch = row0>>10, brow0 = row0&1023;

  // ================= phase A: attention (4 iterations per wave) =================
  f32x4 oacc[4] = {};
  float m_r[4] = {-3e38f,-3e38f,-3e38f,-3e38f};
  float l_r[4] = {0.f,0.f,0.f,0.f};
  {
    int h = w>>2, g = w&3;
    int z = batch*HEADS_ + h;
    const u16* qp = qb + ((long long)row0 + lr)*DIM_ + h*DH_;
    bf16x8 aq0 = *(const bf16x8*)(qp + qd*8);
    bf16x8 aq1 = *(const bf16x8*)(qp + 32 + qd*8);

    const u16* kbase = kvb + ((long long)(batch*N_))*512 + h*DH_;
    const u16* vbase = vt + (long long)batch*(DIM_*N_) + (long long)(h*DH_)*N_;
    const u16* bias_base = bsum + ((long long)z*N_ + brow0)*(long long)N_;
    int srr = lane>>2, scc = (lane&3)*16;

    for (int jtl=0; jtl<4; jtl++){
      int j0 = (g*4 + jtl)*64;
      {
        const u16* gs = bias_base + (long long)srr*N_ + j0 + scc;
        uint4 t0 = *(const uint4*)gs;
        uint4 t1 = *(const uint4*)(gs+8);
        *(uint4*)&sb[w][srr][scc]   = t0;
        *(uint4*)&sb[w][srr][scc+8] = t1;
      }
      f32x4 sacc[4] = {};
      #pragma unroll
      for (int nt=0; nt<4; nt++){
        const u16* kp = kbase + (long long)(j0 + nt*16 + lr)*512;
        bf16x8 bk0 = *(const bf16x8*)(kp + qd*8);
        bf16x8 bk1 = *(const bf16x8*)(kp + 32 + qd*8);
        sacc[nt] = MFMA16(aq0, bk0, sacc[nt]);
        sacc[nt] = MFMA16(aq1, bk1, sacc[nt]);
      }
      #pragma unroll
      for (int r=0;r<4;r++){
        float pv[4];
        float vmax = -3e38f;
        #pragma unroll
        for (int nt=0;nt<4;nt++){
          float v = sacc[nt][r]*0.0625f + r2f(sb[w][qd*4+r][nt*16+lr]);
          pv[nt] = v;
          vmax = fmaxf(vmax, v);
        }
        vmax = fmaxf(vmax, __shfl_xor(vmax,1));
        vmax = fmaxf(vmax, __shfl_xor(vmax,2));
        vmax = fmaxf(vmax, __shfl_xor(vmax,4));
        vmax = fmaxf(vmax, __shfl_xor(vmax,8));
        float newm = fmaxf(m_r[r], vmax);
        float alpha = __expf(m_r[r]-newm);
        m_r[r] = newm;
        float psum = 0.f;
        #pragma unroll
        for (int nt=0;nt<4;nt++){
          float p = __expf(pv[nt]-newm);
          psum += p;
          Pl[w][qd*4+r][nt*16+lr] = f2r(p);
        }
        psum += __shfl_xor(psum,1);
        psum += __shfl_xor(psum,2);
        psum += __shfl_xor(psum,4);
        psum += __shfl_xor(psum,8);
        l_r[r] = l_r[r]*alpha + psum;
        #pragma unroll
        for (int ot=0;ot<4;ot++) oacc[ot][r] *= alpha;
      }
      #pragma unroll
      for (int ks=0;ks<2;ks++){
        bf16x8 ap = *(const bf16x8*)&Pl[w][lr][ks*32 + qd*8];
        #pragma unroll
        for (int ot=0;ot<4;ot++){
          const u16* vp = vbase + (long long)(ot*16+lr)*N_ + j0 + ks*32 + qd*8;
          bf16x8 bv = *(const bf16x8*)vp;
          oacc[ot] = MFMA16(ap, bv, oacc[ot]);
        }
      }
    }
  }
  __syncthreads();   // all waves done with sb/Pl -> Ol may overlay
  #pragma unroll
  for (int r=0;r<4;r++){
    int row = qd*4+r;
    #pragma unroll
    for (int ot=0;ot<4;ot++) Ol[w][row][ot*16+lr] = oacc[ot][r];
    if (lr==0){ Ml[w][row] = m_r[r]; Ll[w][row] = l_r[r]; }
  }
  __syncthreads();
  // ---- 4-way merge (waves with g==0) -> ao_s (bf16)
  if ((w&3)==0){
    int h = w>>2;
    #pragma unroll
    for (int r=0;r<4;r++){
      int row = qd*4+r;
      float m0 = Ml[w][row], m1 = Ml[w+1][row], m2 = Ml[w+2][row], m3 = Ml[w+3][row];
      float mm = fmaxf(fmaxf(m0,m1), fmaxf(m2,m3));
      float e0 = __expf(m0-mm), e1 = __expf(m1-mm), e2 = __expf(m2-mm), e3 = __expf(m3-mm);
      float inv = 1.0f/(Ll[w][row]*e0 + Ll[w+1][row]*e1 + Ll[w+2][row]*e2 + Ll[w+3][row]*e3);
      #pragma unroll
      for (int ot=0;ot<4;ot++){
        int c = ot*16+lr;
        float o = Ol[w][row][c]*e0 + Ol[w+1][row][c]*e1 + Ol[w+2][row][c]*e2 + Ol[w+3][row][c]*e3;
        ao_s[row][h*DH_ + c] = f2r(o*inv);
      }
    }
  }
  __syncthreads();

  // ================= phase B (1024 thr): Wo+res -> LN2 -> W1+gelu -> W2+res -> LN1' =================
  // ---- stage1: x' = ao@Wo + bo + resx -> v_s  (kw K-half, reduce in v_s)
  {
    int kw = w>>3, cw = w&7;
    f32x4 acc[2] = {};
    for (int k0=0;k0<128;k0+=32){
      bf16x8 af = *(const bf16x8*)&ao_s[lr][kw*128 + k0 + qd*8];
      #pragma unroll
      for (int i=0;i<2;i++){
        int cv = cw*2+i;
        bf16x8 bf = *(const bf16x8*)(WoT + (long long)(cv*16+lr)*256 + kw*128 + k0 + qd*8);
        acc[i] = MFMA16(af,bf,acc[i]);
      }
    }
    if (kw==0){
      #pragma unroll
      for (int i=0;i<2;i++)
        #pragma unroll
        for (int r=0;r<4;r++) v_s[qd*4+r][(cw*2+i)*16+lr] = acc[i][r];
    }
    __syncthreads();
    if (kw==1){
      #pragma unroll
      for (int i=0;i<2;i++){
        int col = (cw*2+i)*16+lr;
        #pragma unroll
        for (int r=0;r<4;r++)
          v_s[qd*4+r][col] = v_s[qd*4+r][col] + acc[i][r] + bo[col]
                           + resx[(long long)(row0+qd*4+r)*DIM_ + col];
      }
    }
    __syncthreads();
  }
  // ---- LN2 -> xn2_s
  {
    int r = tid>>6, c0 = (tid&63)*4;
    float v[4]; float s=0.f;
    #pragma unroll
    for (int i=0;i<4;i++){ v[i] = v_s[r][c0+i]; s += v[i]; }
    s += __shfl_xor(s,1); s += __shfl_xor(s,2); s += __shfl_xor(s,4);
    s += __shfl_xor(s,8); s += __shfl_xor(s,16); s += __shfl_xor(s,32);
    float mu = s*(1.0f/256.0f);
    float s2=0.f;
    #pragma unroll
    for (int i=0;i<4;i++){ float d=v[i]-mu; s2 += d*d; }
    s2 += __shfl_xor(s2,1); s2 += __shfl_xor(s2,2); s2 += __shfl_xor(s2,4);
    s2 += __shfl_xor(s2,8); s2 += __shfl_xor(s2,16); s2 += __shfl_xor(s2,32);
    float rstd = rsqrtf(s2*(1.0f/256.0f)+1e-5f);
    #pragma unroll
    for (int i=0;i<4;i++){
      int c = c0+i;
      xn2_s[r][c] = f2r((v[i]-mu)*rstd*ln2g[c] + ln2b[c]);
    }
  }
  __syncthreads();
  // ---- stage2: h1 = gelu(xn2 @ W1 + b1) -> h1_s  (16 waves x 4 tiles, full K)
  {
    f32x4 acc[4] = {};
    for (int k0=0;k0<256;k0+=32){
      bf16x8 af = *(const bf16x8*)&xn2_s[lr][k0+qd*8];
      #pragma unroll
      for (int i=0;i<4;i++){
        int cv = w*4+i;
        bf16x8 bf = *(const bf16x8*)(W1T + (long long)(cv*16+lr)*256 + k0 + qd*8);
        acc[i] = MFMA16(af,bf,acc[i]);
      }
    }
    #pragma unroll
    for (int i=0;i<4;i++){
      int col = (w*4+i)*16+lr;
      #pragma unroll
      for (int r=0;r<4;r++)
        h1_s[qd*4+r][col] = f2r(gelu_exact(acc[i][r] + b1[col]));
    }
  }
  __syncthreads();
  // ---- stage3: x_new = h1 @ W2 + b2 + x' -> xf_out (+ xnew_s)  (kw K-half of 512)
  {
    int kw = w>>3, cw = w&7;
    f32x4 acc[2] = {};
    for (int k0=0;k0<512;k0+=32){
      bf16x8 af = *(const bf16x8*)&h1_s[lr][kw*512 + k0 + qd*8];
      #pragma unroll
      for (int i=0;i<2;i++){
        int cv = cw*2+i;
        bf16x8 bf = *(const bf16x8*)(W2T + (long long)(cv*16+lr)*1024 + kw*512 + k0 + qd*8);
        acc[i] = MFMA16(af,bf,acc[i]);
      }
    }
    if (kw==0){
      #pragma unroll
      for (int i=0;i<2;i++)
        #pragma unroll
        for (int r=0;r<4;r++) xnew_s[qd*4+r][(cw*2+i)*16+lr] = acc[i][r];
    }
    __syncthreads();
    if (kw==1){
      #pragma unroll
      for (int i=0;i<2;i++){
        int col = (cw*2+i)*16+lr;
        #pragma unroll
        for (int r=0;r<4;r++){
          float v = xnew_s[qd*4+r][col] + acc[i][r] + b2[col] + v_s[qd*4+r][col];
          xf_out[(long long)(row0+qd*4+r)*DIM_ + col] = v;
          xnew_s[qd*4+r][col] = v;
        }
      }
    }
  }
  if (ln1g_next){
    __syncthreads();
    int r = tid>>6, c0 = (tid&63)*4;
    float v[4]; float s=0.f;
    #pragma unroll
    for (int i=0;i<4;i++){ v[i] = xnew_s[r][c0+i]; s += v[i]; }
    s += __shfl_xor(s,1); s += __shfl_xor(s,2); s += __shfl_xor(s,4);
    s += __shfl_xor(s,8); s += __shfl_xor(s,16); s += __shfl_xor(s,32);
    float mu = s*(1.0f/256.0f);
    float s2=0.f;
    #pragma unroll
    for (int i=0;i<4;i++){ float d=v[i]-mu; s2 += d*d; }
    s2 += __shfl_xor(s2,1); s2 += __shfl_xor(s2,2); s2 += __shfl_xor(s2,4);
    s2 += __shfl_xor(s2,8); s2 += __shfl_xor(s2,16); s2 += __shfl_xor(s2,32);
    float rstd = rsqrtf(s2*(1.0f/256.0f)+1e-5f);
    int grow = row0 + r;
    #pragma unroll
    for (int i=0;i<4;i++){
      int c = c0+i;
      xn_out[(long long)grow*DIM_ + c] = f2r((v[i]-mu)*rstd*ln1g_next[c] + ln1b_next[c]);
      xT_out[(long long)batch*262144 + (long long)c*1024 + (grow&1023)] = f2r(v[i]);
    }
  }
}

// ---------------- host launch ----------------
extern "C" void kernel_launch(void* const* d_in, const int* in_sizes, int n_in,
                              void* d_out, int out_size, void* d_ws, size_t ws_size,
                              hipStream_t stream){
  const float* x_in   = (const float*)d_in[0];
  const float* abias  = (const float*)d_in[1];
  const float* ln1_g  = (const float*)d_in[2];
  const float* ln1_b  = (const float*)d_in[3];
  const float* Wkv    = (const float*)d_in[4];
  const float* Wq     = (const float*)d_in[5];
  const float* Wo     = (const float*)d_in[6];
  const float* bo     = (const float*)d_in[7];
  const float* ln2_g  = (const float*)d_in[8];
  const float* ln2_b  = (const float*)d_in[9];
  const float* W1     = (const float*)d_in[10];
  const float* b1     = (const float*)d_in[11];
  const float* W2     = (const float*)d_in[12];
  const float* b2     = (const float*)d_in[13];
  const float* Wg     = (const float*)d_in[14];
  const float* lng_g  = (const float*)d_in[15];
  const float* lng_b  = (const float*)d_in[16];

  char* ws = (char*)d_ws;
  float* xf   = (float*)(ws);                               // 4 MB fp32 residual
  u16*  Gb    = (u16*)(ws + (4ll<<20));                     // 8 MB
  u16*  bsum  = (u16*)(ws + (12ll<<20));                    // 32 MB
  u16*  kvb   = (u16*)(ws + (44ll<<20));                    // 4 MB
  u16*  vt    = (u16*)(ws + (48ll<<20));                    // 2 MB
  u16*  xT    = (u16*)(ws + (50ll<<20));                    // 2 MB
  u16*  xnb   = (u16*)(ws + (52ll<<20));                    // 2 MB
  u16*  qb    = (u16*)(ws + (54ll<<20));                    // 2 MB
  u16*  WkvT  = (u16*)(ws + (58ll<<20));                    // 1 MB
  u16*  WqT   = (u16*)(ws + (59ll<<20));                    // 0.5 MB
  u16*  WoT   = (u16*)(ws + (59ll<<20) + (512ll<<10));      // 0.5 MB
  u16*  W1T   = (u16*)(ws + (60ll<<20));                    // 2 MB
  u16*  W2T   = (u16*)(ws + (62ll<<20));                    // 2 MB
  u16*  WgT   = (u16*)(ws + (64ll<<20));                    // 0.125 MB

  prep_fused<<<dim3(4608), dim3(256), 0, stream>>>(abias, Gb, bsum, x_in, xnb, ln1_g, ln1_b);
  tcast_all<<<dim3(32,32,25), dim3(32,8), 0, stream>>>(Wkv,Wq,Wo,W1,W2,Wg,x_in,
                                                       WkvT,WqT,WoT,W1T,W2T,WgT,xT);

  for (int l=0; l<DEPTH_; l++){
    const float* resx = (l==0) ? x_in : xf;
    layer_pre<<<dim3(512), dim3(512), 0, stream>>>(Gb, xT, xnb,
        WgT, WqT + (long long)l*65536, WkvT + (long long)l*131072,
        lng_g, lng_b, qb, kvb, vt);
    if (l < DEPTH_-1){
      attn_post<<<dim3(256), dim3(1024), 0, stream>>>(qb, kvb, vt, bsum, resx,
          WoT + (long long)l*65536, bo + l*DIM_, ln2_g + l*DIM_, ln2_b + l*DIM_,
          W1T + (long long)l*262144, b1 + l*MLP_, W2T + (long long)l*262144, b2 + l*DIM_,
          xf, ln1_g + (l+1)*DIM_, ln1_b + (l+1)*DIM_, xnb, xT);
    } else {
      attn_post<<<dim3(256), dim3(1024), 0, stream>>>(qb, kvb, vt, bsum, resx,
          WoT + (long long)l*65536, bo + l*DIM_, ln2_g + l*DIM_, ln2_b + l*DIM_,
          W1T + (long long)l*262144, b1 + l*MLP_, W2T + (long long)l*262144, b2 + l*DIM_,
          (float*)d_out, nullptr, nullptr, nullptr, nullptr);
    }
  }
}